// Round 7
// baseline (170.837 us; speedup 1.0000x reference)
//
#include <hip/hip_runtime.h>
#include <hip/hip_bf16.h>

// GCNConv: out = D^-1/2 (A+I) D^-1/2 (X W) + b
// N=100000, E=1600000, IN=128, OUT=64. edge_index int32, [row(E) | col(E)].
//
// Pipeline v15 — v14 layout, single-node guarded aggregate, vectorized prep:
//   0. wprep:       W fp32 [k][n] -> wbt bf16 [n][k]; cursor[b] = b*PSTRIDE
//   1. place:       int4-vectorized LDS hist -> span reservation -> scatter
//   2. bucket_sort: counting sort into FIXED 32 slots/node (sentinel n pad,
//                   deg>32 -> overflow list); uint4 copy-out; degb + dinv
//   3. gemm:        MFMA 16x16x32 bf16; hp_bf16 = (dinv*x) @ W; row n = zeros
//   4. aggregate:   wave per node (v13 shape): iv=csr[wid*32+l31] (1 line),
//                   self/dinv/deg in parallel, ceil(min(deg,32)/8) wave-uniform
//                   guarded dwordx4 gathers (kills v13's ~45% sentinel
//                   addresses), 8-acc butterfly (half of v14's 16-acc cost).

#define IN_CH 128
#define OUT_CH 64
#define BSHIFT 7            // 128 nodes per bucket
#define BNODES 128
#define MAX_NB 800
#define CH_EDGES 8192       // edges per partition block (2 rounds x 1024 x int4)
#define PSTRIDE 4096        // ints per bucket in pairs (unpadded, avg 2046)
#define SLOTS 32            // fixed csr slots per node
#define SORT_CAP (BNODES * SLOTS)   // 4096 ints = 16 KB
#define OVSTRIDE 512        // per-bucket overflow capacity (deg>32 spill)
#define XSTR 136            // bf16 LDS row stride: 272B -> conflict-free b128

typedef short bf16x8 __attribute__((ext_vector_type(8)));
typedef float f32x4  __attribute__((ext_vector_type(4)));

__device__ __forceinline__ unsigned short f2b(float f) {   // RNE fp32->bf16
    unsigned int u = __float_as_uint(f);
    return (unsigned short)((u + 0x7FFFu + ((u >> 16) & 1u)) >> 16);
}

__device__ __forceinline__ float blo(unsigned u) { return __uint_as_float(u << 16); }
__device__ __forceinline__ float bhi(unsigned u) { return __uint_as_float(u & 0xFFFF0000u); }

// ---------------- 0: W fp32 [k][n] -> bf16 [n][k]; init cursors ----------
__global__ __launch_bounds__(256) void wprep_kernel(const float* __restrict__ W,
                                                    unsigned short* __restrict__ wbt,
                                                    int* __restrict__ cursor,
                                                    int NB) {
    int t = blockIdx.x * 256 + threadIdx.x;   // 8192 threads
    int k = t >> 6, nn = t & 63;
    wbt[nn * IN_CH + k] = f2b(W[t]);
    if (t < NB) cursor[t] = t * PSTRIDE;
}

// ---------------- 1: place into pairs (int4 reads, LDS hist, reservation) ---
__global__ __launch_bounds__(1024) void place_kernel(const int* __restrict__ row,
                                                     const int* __restrict__ col,
                                                     int* __restrict__ cursor,
                                                     int* __restrict__ pairs,
                                                     int E, int NB) {
    __shared__ int h[MAX_NB];
    int tid = threadIdx.x;
    for (int i = tid; i < NB; i += 1024) h[i] = 0;
    __syncthreads();
    int e0 = blockIdx.x * CH_EDGES;
    // E % 4 == 0 and e is 4-aligned, so (e < E) <=> (e+3 < E)
    #pragma unroll
    for (int r1 = 0; r1 < CH_EDGES / 4096; ++r1) {
        int e = e0 + (r1 * 1024 + tid) * 4;
        if (e < E) {
            int4 c4 = *(const int4*)(col + e);
            atomicAdd(&h[c4.x >> BSHIFT], 1);
            atomicAdd(&h[c4.y >> BSHIFT], 1);
            atomicAdd(&h[c4.z >> BSHIFT], 1);
            atomicAdd(&h[c4.w >> BSHIFT], 1);
        }
    }
    __syncthreads();
    // reserve a contiguous span per (bucket, block); h[i] becomes local cursor
    for (int i = tid; i < NB; i += 1024) {
        int c = h[i];
        if (c) h[i] = atomicAdd(&cursor[i], c);
    }
    __syncthreads();
    #pragma unroll
    for (int r2 = 0; r2 < CH_EDGES / 4096; ++r2) {
        int e = e0 + (r2 * 1024 + tid) * 4;
        if (e < E) {
            int4 c4 = *(const int4*)(col + e);
            int4 r4 = *(const int4*)(row + e);
            int b0 = c4.x >> BSHIFT, b1 = c4.y >> BSHIFT;
            int b2 = c4.z >> BSHIFT, b3 = c4.w >> BSHIFT;
            int p0 = atomicAdd(&h[b0], 1);
            pairs[p0] = r4.x | ((c4.x & (BNODES - 1)) << 17);
            int p1 = atomicAdd(&h[b1], 1);
            pairs[p1] = r4.y | ((c4.y & (BNODES - 1)) << 17);
            int p2 = atomicAdd(&h[b2], 1);
            pairs[p2] = r4.z | ((c4.z & (BNODES - 1)) << 17);
            int p3 = atomicAdd(&h[b3], 1);
            pairs[p3] = r4.w | ((c4.w & (BNODES - 1)) << 17);
        }
    }
}

// ---------------- 2: per-bucket counting sort into fixed 32 slots/node ------
// csr[node*32 + i]: first min(deg,32) = real source rows, rest = sentinel n.
// deg>32 spills to ovpairs[bucket*OVSTRIDE + ...] (+ ovcnt[bucket]).
// degb[node] = min(deg,255). dinv from TRUE deg.
__global__ __launch_bounds__(256) void bucket_sort_kernel(
    const int* __restrict__ cursor_end, const int* __restrict__ pairs,
    int* __restrict__ csr, int* __restrict__ ovpairs, int* __restrict__ ovcnt,
    unsigned char* __restrict__ degb, float* __restrict__ dinv, int n)
{
    __shared__ int cnt[BNODES];
    __shared__ int cur[BNODES];
    __shared__ __align__(16) int sorted[SORT_CAP];   // 16 KB
    __shared__ int ovl[OVSTRIDE];      // 2 KB
    __shared__ int ovc;

    int b = blockIdx.x, tid = threadIdx.x;
    int node0 = b << BSHIFT;
    int nodeCnt = min(BNODES, n - node0);
    int s0 = b * PSTRIDE;
    int m  = cursor_end[b] - s0;

    if (tid < BNODES) { cnt[tid] = 0; cur[tid] = 0; }
    if (tid == 0) ovc = 0;
    __syncthreads();
    for (int e = tid; e < m; e += 256) atomicAdd(&cnt[pairs[s0 + e] >> 17], 1);
    // sentinel prefill (independent of histogram)
    #pragma unroll
    for (int i = 0; i < SORT_CAP / 256; ++i) sorted[tid + i * 256] = n;
    __syncthreads();
    if (tid < nodeCnt) {
        int d = cnt[tid];
        degb[node0 + tid] = (unsigned char)min(d, 255);
        dinv[node0 + tid] = rsqrtf((float)(d + 1));   // +1 self loop
    }
    __syncthreads();
    for (int e = tid; e < m; e += 256) {
        int p   = pairs[s0 + e];
        int lc  = p >> 17;
        int pos = atomicAdd(&cur[lc], 1);
        if (pos < SLOTS) sorted[lc * SLOTS + pos] = p & 0x1FFFF;
        else {
            int o = atomicAdd(&ovc, 1);
            if (o < OVSTRIDE) ovl[o] = p;             // (lcol<<17)|row
        }
    }
    __syncthreads();
    {   // coalesced copy-out: 16 KB as uint4 (4x fewer instructions)
        uint4* dst = (uint4*)(csr + node0 * SLOTS);
        const uint4* src = (const uint4*)sorted;
        #pragma unroll
        for (int i = 0; i < SORT_CAP / 1024; ++i)
            dst[tid + i * 256] = src[tid + i * 256];
    }
    int oc = min(ovc, OVSTRIDE);
    if (tid == 0) ovcnt[b] = oc;
    for (int i = tid; i < oc; i += 256) ovpairs[b * OVSTRIDE + i] = ovl[i];
}

// ---------------- 3: MFMA GEMM  hp_bf16 = (dinv*x) @ W  (+ zero row n) ------
// 256 thr = 4 waves; 64-row tile; wave w does rows w*16..w*16+15 x all 64 cols.
__global__ __launch_bounds__(256) void gemm_kernel(
    const float* __restrict__ x, const unsigned short* __restrict__ wbt,
    const float* __restrict__ dinv, unsigned short* __restrict__ hpb, int n)
{
    __shared__ __align__(16) unsigned short xl[64 * XSTR];  // 17408 B
    __shared__ __align__(16) unsigned short wl[64 * XSTR];  // W^T: [n][k]

    int tid  = threadIdx.x;
    int row0 = blockIdx.x * 64;

    {
        const uint4* src = (const uint4*)wbt;
        #pragma unroll
        for (int i = 0; i < 4; ++i) {
            int flat = tid + i * 256;
            int nn = flat >> 4, c = flat & 15;
            *(uint4*)(wl + nn * XSTR + c * 8) = src[flat];
        }
    }
    #pragma unroll
    for (int i = 0; i < 4; ++i) {
        int r  = (tid >> 4) + i * 16;
        int c  = tid & 15;
        int gr = row0 + r;
        float4 v0 = make_float4(0.f,0.f,0.f,0.f), v1 = v0;
        float d = 0.f;
        if (gr < n) {
            d = dinv[gr];
            const float4* xr = (const float4*)(x + (size_t)gr * IN_CH);
            v0 = xr[c * 2]; v1 = xr[c * 2 + 1];
        }
        uint4 p;
        p.x = ((unsigned)f2b(v0.y * d) << 16) | f2b(v0.x * d);
        p.y = ((unsigned)f2b(v0.w * d) << 16) | f2b(v0.z * d);
        p.z = ((unsigned)f2b(v1.y * d) << 16) | f2b(v1.x * d);
        p.w = ((unsigned)f2b(v1.w * d) << 16) | f2b(v1.z * d);
        *(uint4*)(xl + r * XSTR + c * 8) = p;
    }
    __syncthreads();

    int lane = tid & 63, w = tid >> 6;
    int mrow = lane & 15;
    int g    = lane >> 4;

    f32x4 acc0 = {0,0,0,0}, acc1 = {0,0,0,0}, acc2 = {0,0,0,0}, acc3 = {0,0,0,0};
    const unsigned short* xbase = xl + (w * 16 + mrow) * XSTR + g * 8;
    const unsigned short* wbase = wl + mrow * XSTR + g * 8;

    #pragma unroll
    for (int k4 = 0; k4 < 4; ++k4) {
        bf16x8 a  = *(const bf16x8*)(xbase + k4 * 32);
        bf16x8 b0 = *(const bf16x8*)(wbase +             k4 * 32);
        bf16x8 b1 = *(const bf16x8*)(wbase + 16 * XSTR + k4 * 32);
        bf16x8 b2 = *(const bf16x8*)(wbase + 32 * XSTR + k4 * 32);
        bf16x8 b3 = *(const bf16x8*)(wbase + 48 * XSTR + k4 * 32);
        acc0 = __builtin_amdgcn_mfma_f32_16x16x32_bf16(a, b0, acc0, 0, 0, 0);
        acc1 = __builtin_amdgcn_mfma_f32_16x16x32_bf16(a, b1, acc1, 0, 0, 0);
        acc2 = __builtin_amdgcn_mfma_f32_16x16x32_bf16(a, b2, acc2, 0, 0, 0);
        acc3 = __builtin_amdgcn_mfma_f32_16x16x32_bf16(a, b3, acc3, 0, 0, 0);
    }
    __syncthreads();   // done reading xl; reuse it for the C tile

    {
        int cm = g * 4;
        #pragma unroll
        for (int r = 0; r < 4; ++r) {
            unsigned short* crow = xl + (w * 16 + cm + r) * XSTR + mrow;
            crow[ 0] = f2b(acc0[r]);
            crow[16] = f2b(acc1[r]);
            crow[32] = f2b(acc2[r]);
            crow[48] = f2b(acc3[r]);
        }
    }
    __syncthreads();
    #pragma unroll
    for (int i = 0; i < 2; ++i) {
        int flat = tid + i * 256;
        int r = flat >> 3, c = flat & 7;
        int gr = row0 + r;
        if (gr <= n) {     // row n = sentinel zero row for padded aggregation
            uint4 v = *(const uint4*)(xl + r * XSTR + c * 8);
            *(uint4*)(hpb + (size_t)gr * OUT_CH + c * 8) = v;
        }
    }
}

// ---------------- 4: aggregate — wave/node, guarded gathers, fixed-32 -------
// lane = (e = edge slot 0..7, c = 16B chunk 0..7).
// iv = csr[wid*32 + (lane&31)] : ONE 128B line; self/dinv/deg issue in
// parallel (no dependent chain). Gather g uses rows shfl(iv, g*8+e), guarded
// by wave-uniform rnds = ceil(min(deg,32)/8) -> no sentinel gathers.
__global__ __launch_bounds__(256) void aggregate_kernel(
    const int* __restrict__ csr, const int* __restrict__ ovpairs,
    const int* __restrict__ ovcnt, const unsigned char* __restrict__ degb,
    const unsigned short* __restrict__ hpb, const float* __restrict__ dinv,
    const float* __restrict__ bias, float* __restrict__ out, int n)
{
    int wid  = (blockIdx.x * 256 + threadIdx.x) >> 6;   // node id
    int lane = threadIdx.x & 63;
    if (wid >= n) return;
    int e   = lane >> 3;
    int c   = lane & 7;
    int l31 = lane & 31;

    const uint4* hp16 = (const uint4*)hpb;   // row = 8 x uint4

    // independent loads — all issue before any dependency:
    int iv = csr[wid * SLOTS + l31];
    float d = dinv[wid];
    int deg = degb[wid];
    int bno = wid >> BSHIFT;
    int oc  = ovcnt[bno];
    uint4 sv = hp16[(unsigned)(wid * 8 + c)];           // self-loop chunk (1 line)

    int rnds = (min(deg, SLOTS) + 7) >> 3;              // 0..4, wave-uniform

    float axl=0.f,axh=0.f, ayl=0.f,ayh=0.f, azl=0.f,azh=0.f, awl=0.f,awh=0.f;

    #define GATHER(SRC) \
        { int r_ = __shfl(iv, (SRC));                                            \
          uint4 v_ = hp16[(unsigned)(r_ * 8 + c)];                               \
          axl += blo(v_.x); axh += bhi(v_.x);                                    \
          ayl += blo(v_.y); ayh += bhi(v_.y);                                    \
          azl += blo(v_.z); azh += bhi(v_.z);                                    \
          awl += blo(v_.w); awh += bhi(v_.w); }

    if (rnds > 0) GATHER(     e)
    if (rnds > 1) GATHER( 8 + e)
    if (rnds > 2) GATHER(16 + e)
    if (rnds > 3) GATHER(24 + e)
    #undef GATHER

    if (oc > 0) {                     // rare (deg>32 spill), wave-uniform
        const int* op = ovpairs + bno * OVSTRIDE;
        for (int i = 0; i < oc; ++i) {
            int p    = op[i];
            int node = (bno << BSHIFT) + (p >> 17);
            if (node == wid) {
                uint4 v = hp16[(unsigned)((p & 0x1FFFF) * 8 + c)];
                if (e == 0) {         // count once across the 8 e-slots
                    axl += blo(v.x); axh += bhi(v.x); ayl += blo(v.y); ayh += bhi(v.y);
                    azl += blo(v.z); azh += bhi(v.z); awl += blo(v.w); awh += bhi(v.w);
                }
            }
        }
    }

    // reduce across the 8 edge slots (lanes c, c+8, ..., c+56)
    #pragma unroll
    for (int m = 8; m < 64; m <<= 1) {
        axl += __shfl_xor(axl, m); axh += __shfl_xor(axh, m);
        ayl += __shfl_xor(ayl, m); ayh += __shfl_xor(ayh, m);
        azl += __shfl_xor(azl, m); azh += __shfl_xor(azh, m);
        awl += __shfl_xor(awl, m); awh += __shfl_xor(awh, m);
    }

    if (e == 0) {              // lanes 0..7 finalize chunk c = channels 8c..8c+7
        axl += blo(sv.x); axh += bhi(sv.x);
        ayl += blo(sv.y); ayh += bhi(sv.y);
        azl += blo(sv.z); azh += bhi(sv.z);
        awl += blo(sv.w); awh += bhi(sv.w);
        float4 b0 = ((const float4*)bias)[2 * c];
        float4 b1 = ((const float4*)bias)[2 * c + 1];
        float4 o0, o1;
        o0.x = fmaf(d, axl, b0.x); o0.y = fmaf(d, axh, b0.y);
        o0.z = fmaf(d, ayl, b0.z); o0.w = fmaf(d, ayh, b0.w);
        o1.x = fmaf(d, azl, b1.x); o1.y = fmaf(d, azh, b1.y);
        o1.z = fmaf(d, awl, b1.z); o1.w = fmaf(d, awh, b1.w);
        float* op = out + (size_t)wid * OUT_CH + c * 8;
        *(float4*)op       = o0;
        *(float4*)(op + 4) = o1;
    }
}

extern "C" void kernel_launch(void* const* d_in, const int* in_sizes, int n_in,
                              void* d_out, int out_size, void* d_ws, size_t ws_size,
                              hipStream_t stream) {
    const float* x  = (const float*)d_in[0];
    const int*   ei = (const int*)d_in[1];
    const float* W  = (const float*)d_in[2];
    const float* b  = (const float*)d_in[3];
    float*       out = (float*)d_out;

    int n = in_sizes[0] / IN_CH;     // 100000
    int E = in_sizes[1] / 2;         // 1600000
    const int* row = ei;
    const int* col = ei + E;

    int NB   = (n + BNODES - 1) >> BSHIFT;           // 782
    int NBLK = (E + CH_EDGES - 1) / CH_EDGES;        // 196

    // workspace layout (ws ~= 256 MiB; total used ~45 MB)
    char* ws = (char*)d_ws;
    int*   cursor       = (int*)ws;   ws += (size_t)NB * 4;
    int*   ovcnt        = (int*)ws;   ws += (size_t)NB * 4;
    float* dinv         = (float*)ws; ws += (size_t)n * 4;
    unsigned char* degb = (unsigned char*)ws; ws += (size_t)(n + 2) & ~1ull; ws = (char*)(((uintptr_t)ws + 255) & ~(uintptr_t)255);
    unsigned short* wbt = (unsigned short*)ws; ws += (size_t)IN_CH * OUT_CH * 2;
    ws = (char*)(((uintptr_t)ws + 255) & ~(uintptr_t)255);
    int*   pairs        = (int*)ws;   ws += (size_t)NB * PSTRIDE * 4;   // 12.8 MB
    int*   ovpairs      = (int*)ws;   ws += (size_t)NB * OVSTRIDE * 4;  //  1.6 MB
    int*   csr          = (int*)ws;   ws += (size_t)NB * BNODES * SLOTS * 4; // 12.8 MB
    unsigned short* hpb = (unsigned short*)ws;   // (n+1)*64 bf16 (row n = zeros)

    wprep_kernel      <<<(IN_CH * OUT_CH) / 256, 256, 0, stream>>>(W, wbt, cursor, NB);
    place_kernel      <<<NBLK, 1024, 0, stream>>>(row, col, cursor, pairs, E, NB);
    bucket_sort_kernel<<<NB, 256, 0, stream>>>(cursor, pairs, csr, ovpairs, ovcnt, degb, dinv, n);
    gemm_kernel       <<<(n + 63) / 64, 256, 0, stream>>>(x, wbt, dinv, hpb, n);
    aggregate_kernel  <<<((size_t)n * 64 + 255) / 256, 256, 0, stream>>>(csr, ovpairs, ovcnt, degb, hpb, dinv, b, out, n);
}